// Round 19
// baseline (565.972 us; speedup 1.0000x reference)
//
#include <hip/hip_runtime.h>
#include <hip/hip_bf16.h>
#include <math.h>

#define B_ 128
#define N_ 2048
#define D_ 512
#define H_ 512

#define NEG_BIG (-1.0e30f)

typedef unsigned int uint;
typedef unsigned short ushort;

// ws layout (float offsets)
#define WS_INP  0
#define WS_ATT  (WS_INP + B_*H_)          // 65536
#define WS_M    (WS_ATT + B_*N_)          // +262144  (fallback path only)
#define WS_FLAG (WS_M + B_*D_)            // +65536
#define WS_BP   393280                    // Bpack = 524288 ushort = 1MB
#define WS_U    655424                    // u[B][D] 65536 floats
#define WS_S    720960                    // s[B] 128 floats
#define WS_END  721088
#define WS_MID  655424

typedef __attribute__((ext_vector_type(4))) float  f32x4;
typedef __attribute__((ext_vector_type(8))) short  bf16x8;

union BF8 { unsigned short u[8]; bf16x8 v; };

__device__ __forceinline__ ushort f2bf(float x) {
    uint u = __float_as_uint(x);
    u = (u + 0x7fffu + ((u >> 16) & 1u)) >> 16;   // RNE; inputs finite
    return (ushort)u;
}
__device__ __forceinline__ float bf2f(ushort h) {
    return __uint_as_float(((uint)h) << 16);
}
__device__ __forceinline__ float fast_tanh(float x) {
    return 1.0f - 2.0f / (1.0f + __expf(2.0f * x));
}

// ---------------------------------------------------------------------------
// Fused prep: blocks 0-127 pack Wc; 128-383 inp = x@Wi^T+bi; 384 detect_mask;
// 385-641 (fused path only) zero u[B][D] and s[B].
__global__ __launch_bounds__(256) void prep_kernel(
        const float* __restrict__ Wc, ushort* __restrict__ Bp,
        const float* __restrict__ x, const float* __restrict__ Wi,
        const float* __restrict__ bi, float* __restrict__ inp,
        const uint* __restrict__ mask_raw, int* __restrict__ flag,
        float* __restrict__ gU) {
    const int bid = blockIdx.x;
    const int t   = threadIdx.x;

    if (bid < 128) {                       // ---- pack_wc ----
        int tid = bid * 256 + t;           // 32768 threads
        int lane = tid & 63;
        int fs   = tid >> 6;
        int hf = fs >> 4, ks = fs & 15;
        int h  = hf * 16 + (lane & 15);
        int k0 = ks * 32 + (lane >> 4) * 8;
        const float* src = Wc + (size_t)h * D_ + k0;
        BF8 hi, lo;
#pragma unroll
        for (int j = 0; j < 8; ++j) {
            float xv = src[j];
            hi.u[j] = f2bf(xv);
            lo.u[j] = f2bf(xv - bf2f(hi.u[j]));
        }
        *(bf16x8*)(Bp + (size_t)tid * 8)          = hi.v;
        *(bf16x8*)(Bp + 262144 + (size_t)tid * 8) = lo.v;
    } else if (bid < 384) {                // ---- linear: inp ----
        int idx = (bid - 128) * 256 + t;   // 65536
        int b = idx >> 9;
        int h = idx & (H_ - 1);
        const float4* ar = (const float4*)(x + (size_t)b * D_);
        const float4* wr = (const float4*)(Wi + (size_t)h * D_);
        float acc = 0.f;
#pragma unroll 4
        for (int d = 0; d < D_ / 4; ++d) {
            float4 av = ar[d], wv = wr[d];
            acc = fmaf(av.x, wv.x, acc);
            acc = fmaf(av.y, wv.y, acc);
            acc = fmaf(av.z, wv.z, acc);
            acc = fmaf(av.w, wv.w, acc);
        }
        inp[idx] = acc + bi[h];
    } else if (bid == 384) {               // ---- detect_mask (1 wave) ----
        if (t < 64) {
            uint v = mask_raw[t];
            unsigned long long m = __ballot(v <= 1u);
            if (t == 0) *flag = (m == ~0ull) ? 1 : 0;
        }
    } else {                               // ---- zero u,s (fused only) ----
        int idx = (bid - 385) * 256 + t;
        if (idx < B_ * D_ + B_) gU[idx] = 0.f;
    }
}

// ---------------------------------------------------------------------------
__global__ __launch_bounds__(256) void linear_kernel(
        const float* __restrict__ a, const float* __restrict__ W,
        const float* __restrict__ bias, float* __restrict__ out) {
    int idx = blockIdx.x * 256 + threadIdx.x;
    int b = idx >> 9;
    int h = idx & (H_ - 1);
    const float4* ar = (const float4*)(a + (size_t)b * D_);
    const float4* wr = (const float4*)(W + (size_t)h * D_);
    float acc = 0.f;
#pragma unroll 4
    for (int d = 0; d < D_ / 4; ++d) {
        float4 av = ar[d], wv = wr[d];
        acc = fmaf(av.x, wv.x, acc);
        acc = fmaf(av.y, wv.y, acc);
        acc = fmaf(av.z, wv.z, acc);
        acc = fmaf(av.w, wv.w, acc);
    }
    out[idx] = acc + bias[h];
}

// hidden[b][h] = (sum_d u[b][d]*W[h][d]) / s[b] + bias[h]
__global__ __launch_bounds__(256) void linear_scaled_kernel(
        const float* __restrict__ u, const float* __restrict__ W,
        const float* __restrict__ bias, const float* __restrict__ s,
        float* __restrict__ out) {
    int idx = blockIdx.x * 256 + threadIdx.x;
    int b = idx >> 9;
    int h = idx & (H_ - 1);
    const float4* ar = (const float4*)(u + (size_t)b * D_);
    const float4* wr = (const float4*)(W + (size_t)h * D_);
    float acc = 0.f;
#pragma unroll 4
    for (int d = 0; d < D_ / 4; ++d) {
        float4 av = ar[d], wv = wr[d];
        acc = fmaf(av.x, wv.x, acc);
        acc = fmaf(av.y, wv.y, acc);
        acc = fmaf(av.z, wv.z, acc);
        acc = fmaf(av.w, wv.w, acc);
    }
    out[idx] = acc / s[b] + bias[h];
}

// ---------------------------------------------------------------------------
// Split-bf16 3-product MFMA. BM=64, 512 thr / 8 waves (2r x 4c); wave tile
// 32x128, acc[2][8]=64 -> launch_bounds(512,4): 4 waves/SIMD from TWO blocks
// per CU (LDS only ~17KB) = two independent barrier domains.
// A: conflict-free XOR-slot LDS staging, dbuf 16KB. B: global->reg from
// L2-hot Bpack, software-pipelined in 4 cf-pair groups (r14 pattern).
// Fused tail: u[b][d] += sum_r exp(att_r)*ctx[r][d].
#define KP  32
#define NPH 16

// 4 floats -> hi/lo bf16 (truncation split), two 8B writes
#define STAGE_A64(Ux, bi) do {                                                  \
    uint h0_ = (Ux.y & 0xFFFF0000u) | (Ux.x >> 16);                             \
    uint h1_ = (Ux.w & 0xFFFF0000u) | (Ux.z >> 16);                             \
    float r0_ = __uint_as_float(Ux.x) - __uint_as_float(Ux.x & 0xFFFF0000u);    \
    float r1_ = __uint_as_float(Ux.y) - __uint_as_float(Ux.y & 0xFFFF0000u);    \
    float r2_ = __uint_as_float(Ux.z) - __uint_as_float(Ux.z & 0xFFFF0000u);    \
    float r3_ = __uint_as_float(Ux.w) - __uint_as_float(Ux.w & 0xFFFF0000u);    \
    uint l0_ = (__float_as_uint(r1_) & 0xFFFF0000u) | (__float_as_uint(r0_) >> 16); \
    uint l1_ = (__float_as_uint(r3_) & 0xFFFF0000u) | (__float_as_uint(r2_) >> 16); \
    *(uint2*)((char*)sAh[bi] + aw) = make_uint2(h0_, h1_);                      \
    *(uint2*)((char*)sAl[bi] + aw) = make_uint2(l0_, l1_);                      \
} while (0)

#define MM(a_, b_, c_) __builtin_amdgcn_mfma_f32_16x16x32_bf16(a_, b_, c_, 0, 0, 0)

// load B fragments for column cf (hi+lo) from global (L2-hot)
#define LOADB_G(cf_, BH, BL) do {                                               \
    BH = *(const bf16x8*)(Bpp + bb + (cf_) * 8192);                             \
    BL = *(const bf16x8*)(Bpp + 262144 + bb + (cf_) * 8192);                    \
} while (0)

// 6 MFMAs for one cf (2 row-frags x 3 products)
#define MFMA_CF(cf_, BH, BL) do {                                               \
    acc[0][cf_] = MM(ah0, BH, acc[0][cf_]);                                     \
    acc[1][cf_] = MM(ah1, BH, acc[1][cf_]);                                     \
    acc[0][cf_] = MM(ah0, BL, acc[0][cf_]);                                     \
    acc[1][cf_] = MM(ah1, BL, acc[1][cf_]);                                     \
    acc[0][cf_] = MM(al0, BH, acc[0][cf_]);                                     \
    acc[1][cf_] = MM(al1, BH, acc[1][cf_]);                                     \
} while (0)

#define SB0 __builtin_amdgcn_sched_barrier(0)

__global__ __launch_bounds__(512, 4) void att_mfma_kernel(
        const float* __restrict__ ctx, const ushort* __restrict__ Bp,
        const float* __restrict__ bc, const float* __restrict__ V,
        const float* __restrict__ inp, float* __restrict__ att,
        float* __restrict__ gU, float* __restrict__ gS, int fused) {
    __shared__ ushort sAh[2][2048];    // 8KB  [buf][frag4][slot64][8]
    __shared__ ushort sAl[2][2048];    // 8KB

    const int t    = threadIdx.x;
    const int lane = t & 63;
    const int w    = t >> 6;               // 0..7
    const int wr   = w >> 2;               // 32-row group
    const int wc   = w & 3;                // 128-col group
    const int g0   = blockIdx.x * 64;
    const int b    = g0 >> 11;             // uniform (64 | 2048)

    // A staging: thread t -> row srow = t>>3 (0..63), 4-float chunk kq = t&7
    const int srow = t >> 3;
    const int kq   = t & 7;
    const float* gAs = ctx + (size_t)(g0 + srow) * D_ + kq * 4;
    // dest: frag = srow>>4; lanef = (srow&15) + (kq>>1)*16; XOR-slot; sub 8B
    const int sfrag = srow >> 4;
    const int lanef = (srow & 15) + ((kq >> 1) << 4);
    const int sslot = lanef ^ ((lanef >> 4) & 3);
    const unsigned aw = (unsigned)(sfrag * 1024 + sslot * 16 + (kq & 1) * 8);

    // A fragment read offsets (bytes): frag = wr*2+rf, slot = lane^((lane>>4)&3)
    const int rslot = lane ^ ((lane >> 4) & 3);
    const unsigned ar0 = (unsigned)((wr * 2 + 0) * 1024 + rslot * 16);
    const unsigned ar1 = (unsigned)((wr * 2 + 1) * 1024 + rslot * 16);

    const int bb = wc * 65536 + lane * 8;  // B fragment base (ushort idx)

    f32x4 acc[2][8] = {};

    // prologue: stage A(0)
    {
        uint4 U0 = *(const uint4*)(gAs);
        STAGE_A64(U0, 0);
        __syncthreads();
    }

    for (int p = 0; p < NPH; ++p) {
        const int buf = p & 1;
        const int pn  = (p + 1) & 15;      // uniform; last prefetch dead
        const ushort* Bpp = Bp + (size_t)p * 512;

        // A global prefetch for next phase
        uint4 U = *(const uint4*)(gAs + pn * KP);
        SB0;
        // B group 0 (cf 0,1)
        bf16x8 x0h, x0l, x1h, x1l;
        LOADB_G(0, x0h, x0l); LOADB_G(1, x1h, x1l);
        SB0;
        // A fragments from LDS (overlap B latency)
        bf16x8 ah0 = *(const bf16x8*)((const char*)sAh[buf] + ar0);
        bf16x8 al0 = *(const bf16x8*)((const char*)sAl[buf] + ar0);
        bf16x8 ah1 = *(const bf16x8*)((const char*)sAh[buf] + ar1);
        bf16x8 al1 = *(const bf16x8*)((const char*)sAl[buf] + ar1);
        SB0;
        // B group 1 (cf 2,3)
        bf16x8 y0h, y0l, y1h, y1l;
        LOADB_G(2, y0h, y0l); LOADB_G(3, y1h, y1l);
        SB0;
        __builtin_amdgcn_s_setprio(1);
        MFMA_CF(0, x0h, x0l); MFMA_CF(1, x1h, x1l);
        SB0;
        LOADB_G(4, x0h, x0l); LOADB_G(5, x1h, x1l);   // group 2
        SB0;
        MFMA_CF(2, y0h, y0l); MFMA_CF(3, y1h, y1l);
        SB0;
        LOADB_G(6, y0h, y0l); LOADB_G(7, y1h, y1l);   // group 3
        SB0;
        MFMA_CF(4, x0h, x0l); MFMA_CF(5, x1h, x1l);
        SB0;
        MFMA_CF(6, y0h, y0l); MFMA_CF(7, y1h, y1l);
        __builtin_amdgcn_s_setprio(0);
        SB0;

        STAGE_A64(U, buf ^ 1);             // stage next A (dbuf)
        __syncthreads();
    }

    // epilogue: tanh + V-weight + reduce.  C/D: col=lane&15, row=(lane>>4)*4+j
    float P[2][4] = {};
#pragma unroll
    for (int cf = 0; cf < 8; ++cf) {
        const int h = wc * 128 + cf * 16 + (lane & 15);
        const float sh = inp[b * H_ + h] + bc[h];
        const float vh = V[h];
#pragma unroll
        for (int rf = 0; rf < 2; ++rf)
#pragma unroll
            for (int j = 0; j < 4; ++j)
                P[rf][j] += vh * fast_tanh(acc[rf][cf][j] + sh);
    }
#pragma unroll
    for (int rf = 0; rf < 2; ++rf)
#pragma unroll
        for (int j = 0; j < 4; ++j) {
            float x = P[rf][j];
            x += __shfl_xor(x, 1); x += __shfl_xor(x, 2);
            x += __shfl_xor(x, 4); x += __shfl_xor(x, 8);
            P[rf][j] = x;
        }

    float (*red)[32] = (float(*)[32])sAh;   // 1KB overlay (A dead)
    float* eV = (float*)sAl;                // 256B overlay
    if ((lane & 15) == 0) {
        const int kc = lane >> 4;
#pragma unroll
        for (int rf = 0; rf < 2; ++rf)
#pragma unroll
            for (int j = 0; j < 4; ++j)
                red[w][rf * 16 + kc * 4 + j] = P[rf][j];
    }
    __syncthreads();
    if (t < 64) {
        const int wrr = (t >> 5) * 4, r = t & 31;
        float av = red[wrr + 0][r] + red[wrr + 1][r]
                 + red[wrr + 2][r] + red[wrr + 3][r];
        att[g0 + t] = av;
        eV[t] = __expf(av);                // exp-trick weight
    }
    __syncthreads();

    if (fused) {
        // u[b][d] += sum over this block's 64 rows of e[r]*ctx[row][d]
        const int d = t & 511;
        const float* cp = ctx + (size_t)g0 * D_ + d;
        float acc0 = 0.f;
#pragma unroll 8
        for (int i = 0; i < 64; ++i)
            acc0 = fmaf(eV[i], cp[(size_t)i * D_], acc0);
        atomicAdd(&gU[b * D_ + d], acc0);
        if (t < 64) {
            float sp = eV[t];
            sp += __shfl_xor(sp, 1); sp += __shfl_xor(sp, 2);
            sp += __shfl_xor(sp, 4); sp += __shfl_xor(sp, 8);
            sp += __shfl_xor(sp, 16); sp += __shfl_xor(sp, 32);
            if (t == 0) atomicAdd(&gS[b], sp);
        }
    }
}

// ---------------------------------------------------------------------------
__global__ __launch_bounds__(256) void softmax_kernel(
        const float* __restrict__ att, const void* __restrict__ mask,
        const int* __restrict__ flag, float* __restrict__ alpha,
        float* __restrict__ logp) {
    __shared__ float row[N_];
    __shared__ float red[4];
    const int b = blockIdx.x, t = threadIdx.x;
    const int is_int = *flag;
    const int* mi = (const int*)mask;
    const unsigned char* mb = (const unsigned char*)mask;

    float lmax = -INFINITY;
    for (int n = t; n < N_; n += 256) {
        bool m = is_int ? (mi[b * N_ + n] != 0) : (mb[b * N_ + n] != 0);
        float a = m ? NEG_BIG : att[b * N_ + n];
        row[n] = a;
        lmax = fmaxf(lmax, a);
    }
#pragma unroll
    for (int off = 32; off; off >>= 1) lmax = fmaxf(lmax, __shfl_down(lmax, off));
    if ((t & 63) == 0) red[t >> 6] = lmax;
    __syncthreads();
    const float rmax = fmaxf(fmaxf(red[0], red[1]), fmaxf(red[2], red[3]));
    __syncthreads();

    float lsum = 0.f;
    for (int n = t; n < N_; n += 256) lsum += __expf(row[n] - rmax);
#pragma unroll
    for (int off = 32; off; off >>= 1) lsum += __shfl_down(lsum, off);
    if ((t & 63) == 0) red[t >> 6] = lsum;
    __syncthreads();
    const float s = red[0] + red[1] + red[2] + red[3];
    const float inv = 1.0f / s;
    const float lse = logf(s);

    for (int n = t; n < N_; n += 256) {
        float a = row[n];
        alpha[b * N_ + n] = __expf(a - rmax) * inv;
        logp[b * N_ + n]  = a - rmax - lse;
    }
}

// ---------------------------------------------------------------------------
// Fallback path only (ws too small for fused u/s).
__global__ __launch_bounds__(512) void wsum_kernel(
        const float* __restrict__ context, const float* __restrict__ alpha,
        float* __restrict__ m) {
    __shared__ float al[N_];
    __shared__ float part[3][128];
    const int c = blockIdx.x;
    const int b = blockIdx.y;
    const int t = threadIdx.x;
    for (int n = t; n < N_; n += 512) al[n] = alpha[(size_t)b * N_ + n];
    __syncthreads();
    const int d = c * 128 + (t & 127);
    const int q = t >> 7;
    const float* cp = context + (size_t)b * N_ * D_ + (size_t)q * 512 * D_ + d;
    const float* ap = al + q * 512;
    float acc = 0.f;
#pragma unroll 8
    for (int n = 0; n < 512; ++n) acc = fmaf(ap[n], cp[(size_t)n * D_], acc);
    if (q) part[q - 1][t & 127] = acc;
    __syncthreads();
    if (q == 0)
        m[b * D_ + d] = acc + part[0][t & 127] + part[1][t & 127] + part[2][t & 127];
}

// ---------------------------------------------------------------------------
extern "C" void kernel_launch(void* const* d_in, const int* in_sizes, int n_in,
                              void* d_out, int out_size, void* d_ws, size_t ws_size,
                              hipStream_t stream) {
    const float* x       = (const float*)d_in[0];
    const float* context = (const float*)d_in[1];
    const void*  mask    = d_in[2];
    const float* Wi      = (const float*)d_in[3];
    const float* bi      = (const float*)d_in[4];
    const float* Wc      = (const float*)d_in[5];
    const float* bc      = (const float*)d_in[6];
    const float* V       = (const float*)d_in[7];

    float* out  = (float*)d_out;
    float* ws   = (float*)d_ws;
    float* inp  = ws + WS_INP;
    float* att  = ws + WS_ATT;
    float* m    = ws + WS_M;
    int*   flag = (int*)(ws + WS_FLAG);
    float* gU   = ws + WS_U;
    float* gS   = ws + WS_S;

    float* hidden = out;
    float* alpha  = out + B_ * H_;
    float* logp   = alpha + B_ * N_;

    const bool fused = (ws_size >= (size_t)WS_END * 4);
    const bool bp_ws = (ws_size >= (size_t)(WS_MID + 262144) * 4);
    ushort* Bp = bp_ws ? (ushort*)(ws + WS_BP) : (ushort*)logp;

    prep_kernel<<<fused ? 642 : 385, 256, 0, stream>>>(
        Wc, Bp, x, Wi, bi, inp, (const uint*)mask, flag, gU);
    att_mfma_kernel<<<(B_ * N_) / 64, 512, 0, stream>>>(
        context, Bp, bc, V, inp, att, gU, gS, fused ? 1 : 0);
    softmax_kernel<<<B_, 256, 0, stream>>>(att, mask, flag, alpha, logp);
    if (fused) {
        linear_scaled_kernel<<<256, 256, 0, stream>>>(gU, Wc, bc, gS, hidden);
    } else {
        wsum_kernel<<<dim3(4, B_), 512, 0, stream>>>(context, alpha, m);
        linear_kernel<<<256, 256, 0, stream>>>(m, Wc, bc, hidden);
    }
}